// Round 11
// baseline (309.601 us; speedup 1.0000x reference)
//
#include <hip/hip_runtime.h>
#include <hip/hip_bf16.h>
#include <math.h>

// Problem constants
#define B_SZ   1024
#define D_SZ   512
#define KC_SZ  256
#define NLOW   130816            // 512*511/2

// B pages: per class, 20 K-step pages of 16 KB, stored in per-wave MFMA
// fragment order: line = ((wng*4+ni)*2+h)*64 + lane, lane = q*16+c,
// value[j] = L[d][e], e = wng*64+ni*16+c, d_local = h*32+q*8+j.
#define STEP_ELEMS  8192
#define NSTEPS      20           // 8+6+4+2 triangular K-steps
#define CLASS_ELEMS (NSTEPS * STEP_ELEMS)   // 320 KB/class

// Workspace layout (bytes)
#define OFF_XP     (size_t)(KC_SZ * CLASS_ELEMS * 2)        // 83886080
#define OFF_TPART  (OFF_XP + 64 * STEP_ELEMS * 2)           // +1 MiB
#define OFF_T      (OFF_TPART + (size_t)KC_SZ * 8 * 512 * 4)// +4 MiB
#define WS_NEED    (OFF_T + (size_t)KC_SZ * 512 * 4)        // ~85.5 MiB

typedef __attribute__((ext_vector_type(4))) float  f32x4;
typedef __attribute__((ext_vector_type(4), aligned(4))) float f32x4u; // align-4 vector load
typedef __attribute__((ext_vector_type(8))) __bf16 bf16x8;

// steps before col-tile ct
__device__ __forceinline__ int sbase_of(int ct) { return ct * (9 - ct); }
// s -> dt (also the A-page k-chunk)
__device__ __forceinline__ int kch_of(int s) {
    return (s < 8) ? s : (s < 14) ? s - 6 : (s < 18) ? s - 10 : s - 12;
}

// ---------------------------------------------------------------------------
// K1: fused prep. Blocks [0,64): X pages. Blocks [64, 64+20*256): one B page
// + t-partials per block (round-9 shape). Round-10 lesson: pairing halved
// residency (33 KB LDS -> 2.5 blocks/CU) and was latency-exposed. This round
// removes the 16.5 KB ptl array entirely -- the t-partial reduction over the
// 32 m-lanes is a register shfl_xor butterfly (masks 1..16 stay within the
// 32-lane half) -- so block LDS drops to 16.4 KB -> 8 blocks/CU residency.
// Bp pages bitwise-identical; tpart differs only in fp32 summation order.
// ---------------------------------------------------------------------------
__global__ __launch_bounds__(256)
void prep_all(const float* __restrict__ X,
              const float* __restrict__ Ldiag,
              const float* __restrict__ Llow,
              const float* __restrict__ W,
              __hip_bfloat16* __restrict__ Xp,
              __hip_bfloat16* __restrict__ Bp,
              float* __restrict__ tpart) {
    __shared__ __bf16 Lt[128 * 64];      // [e_local][d_local], 16B-block XOR swizzle

    const int bx  = blockIdx.x;
    const int tid = threadIdx.x;

    if (bx < 64) {
        // ---- prep_x: page pg = bx, 4 lines per thread ----
        const int pg  = bx;              // mt*8 + kch
        const int mt  = pg >> 3, kch = pg & 7;
        __bf16* out = (__bf16*)Xp + (size_t)pg * STEP_ELEMS;
        #pragma unroll
        for (int i = 0; i < 4; ++i) {
            const int line = tid + i * 256;          // 0..1023
            const int wmg = line >> 9, mi = (line >> 7) & 3, h = (line >> 6) & 1;
            const int lane = line & 63, q = lane >> 4, c = lane & 15;
            const int row = mt * 128 + wmg * 64 + mi * 16 + c;
            const float* src = X + (size_t)row * D_SZ + kch * 64 + h * 32 + q * 8;
            f32x4 v0 = ((const f32x4*)src)[0];
            f32x4 v1 = ((const f32x4*)src)[1];
            bf16x8 p;
            #pragma unroll
            for (int j = 0; j < 4; ++j) { p[j] = (__bf16)v0[j]; p[j + 4] = (__bf16)v1[j]; }
            *(bf16x8*)(out + line * 8) = p;
        }
        return;
    }

    // ---- prep_b: page s of class kc ----
    const int idx = bx - 64;
    const int s   = idx % 20;
    const int kc  = idx / 20;
    const int ct = (s < 8) ? 0 : (s < 14) ? 1 : (s < 18) ? 2 : 3;
    const int dt = kch_of(s);
    const int e0 = ct << 7, d0 = dt << 6;

    const int m   = tid & 31;            // d row-pair index
    const int seg = tid >> 5;            // e 16-chunk index
    const int es  = seg << 4;            // e_local chunk start
    const int dg0 = d0 + 2 * m;          // global d of row 0 (row 1 = dg0+1)

    // classify this thread's 16-e chunk:
    // 0 = pure strict-lower (vector loads), 1 = straddles diagonal, 2 = zero
    int cls;
    if (dt >= 2 * ct + 2)      cls = 0;
    else if (dt == 2 * ct + 1) cls = (seg < 4) ? 0 : 1;
    else                       cls = (seg < 4) ? 1 : 2;

    const float* lowb = Llow + (size_t)kc * NLOW;
    const float2 wv = *(const float2*)(W + (size_t)kc * D_SZ + dg0);

    float v0[16], v1[16];
    if (cls == 0) {
        const int t0 = (dg0 * (dg0 - 1)) >> 1;       // tri(dg0)
        const int t1 = t0 + dg0;                     // tri(dg0+1)
        const float* s0 = lowb + t0 + e0 + es;
        const float* s1 = lowb + t1 + e0 + es;
        #pragma unroll
        for (int i = 0; i < 4; ++i) {
            f32x4u a = ((const f32x4u*)s0)[i];
            f32x4u b = ((const f32x4u*)s1)[i];
            #pragma unroll
            for (int j = 0; j < 4; ++j) { v0[i * 4 + j] = a[j]; v1[i * 4 + j] = b[j]; }
        }
    } else if (cls == 1) {
        const int t0 = (dg0 * (dg0 - 1)) >> 1;
        const int t1 = t0 + dg0;
        const float* diagb = Ldiag + (size_t)kc * D_SZ;
        float q0 = diagb[dg0],     q1 = diagb[dg0 + 1];
        q0 *= q0; q1 *= q1;
        #pragma unroll
        for (int j = 0; j < 16; ++j) {
            const int eg = e0 + es + j;
            v0[j] = (eg < dg0)     ? lowb[t0 + eg] : ((eg == dg0)     ? q0 : 0.f);
            v1[j] = (eg < dg0 + 1) ? lowb[t1 + eg] : ((eg == dg0 + 1) ? q1 : 0.f);
        }
    } else {
        #pragma unroll
        for (int j = 0; j < 16; ++j) { v0[j] = 0.f; v1[j] = 0.f; }
    }

    // transposed bf16 pair writes (conflict-free) + per-thread t-products
    char* ltb = (char*)Lt;
    float tp[16];
    #pragma unroll
    for (int j = 0; j < 16; ++j) {
        const int el = es + j;
        union { __bf16 h[2]; unsigned u; } pk;
        pk.h[0] = (__bf16)v0[j];
        pk.h[1] = (__bf16)v1[j];
        const int off = el * 128 + ((4 * m) ^ ((el & 7) << 4));
        *(unsigned*)(ltb + off) = pk.u;
        tp[j] = wv.x * v0[j] + wv.y * v1[j];
    }

    // t-partial reduce over the 32 m-lanes: register butterfly (no LDS).
    // masks 1..16 stay within the 32-lane half holding this seg's m-group.
    #pragma unroll
    for (int j = 0; j < 16; ++j) {
        float v = tp[j];
        v += __shfl_xor(v, 1, 64);
        v += __shfl_xor(v, 2, 64);
        v += __shfl_xor(v, 4, 64);
        v += __shfl_xor(v, 8, 64);
        v += __shfl_xor(v, 16, 64);
        tp[j] = v;
    }
    // lane m (<16) takes slot j==m (compile-time indices only)
    float tsel = 0.f;
    #pragma unroll
    for (int j = 0; j < 16; ++j)
        if (m == j) tsel = tp[j];

    __syncthreads();

    // fragment-order page out: 4 lines/thread, one ds_read_b128 + 16B store each
    __bf16* page = (__bf16*)Bp + (size_t)kc * CLASS_ELEMS + (size_t)s * STEP_ELEMS;
    const int lane = tid & 63, q = lane >> 4, c = lane & 15;
    #pragma unroll
    for (int k = 0; k < 4; ++k) {
        const int ln = k * 256 + tid;
        const int up = ln >> 6;
        const int h  = up & 1;
        const int el = ((up >> 3) << 6) + (((up >> 1) & 3) << 4) + c;
        const int off = el * 128 + (((h << 6) + (q << 4)) ^ ((el & 7) << 4));
        *(bf16x8*)(page + (size_t)ln * 8) = *(const bf16x8*)(ltb + off);
    }

    // tpart write: seg's 16-e chunk, one lane per e
    if (m < 16)
        tpart[((size_t)(kc * 8 + dt)) * 512 + e0 + es + m] = tsel;
}

// ---------------------------------------------------------------------------
// K1c: t[kc][e] = sum over valid dt of tpart[kc][dt][e]  (separate tiny
// launch -- round-7 showed folding this into main's prologue perturbs the
// main loop's schedule: MfmaUtil 43->36, +15 us)
// ---------------------------------------------------------------------------
__global__ __launch_bounds__(256)
void t_reduce(const float* __restrict__ tpart, float* __restrict__ Tv) {
    const int idx = blockIdx.x * 256 + threadIdx.x;   // 131072 total
    const int kc = idx >> 9, e = idx & 511;
    const int ct = e >> 7;
    float s = 0.f;
    for (int dt = ct << 1; dt < 8; ++dt)
        s += tpart[((size_t)(kc * 8 + dt)) * 512 + e];
    Tv[idx] = s;
}

// ---------------------------------------------------------------------------
// K2: main GEMM -- ROUND-3 VERBATIM (measured 85.7 us, VGPR 116, WRITE 3.3 MB,
// MfmaUtil 44%). FROZEN: rounds 4/5/8 prove >128 arch VGPRs spills; round 7
// proves even prologue edits perturb the loop schedule (-15%).
// ---------------------------------------------------------------------------
__global__ __launch_bounds__(256, 2)
void gml2_main(const __hip_bfloat16* __restrict__ Xp,
               const __hip_bfloat16* __restrict__ Bp,
               const float* __restrict__ Tv,
               float* __restrict__ Out) {
    // [buf][ A 16KB | B 16KB ] = 64 KB total; osum aliased after last barrier
    __shared__ __align__(16) char ldsbuf[2][32768];

    const int tid = threadIdx.x;
    const int bx  = blockIdx.x;
    // XCD swizzle: all 8 row-tiles of a class on one XCD -> pages L2-resident
    const int xcd = bx & 7;
    const int g   = bx >> 3;
    const int kc  = xcd * 32 + (g >> 3);
    const int mt  = g & 7;

    const int lane = tid & 63;
    const int wave = tid >> 6;
    const int wmg  = wave & 1;      // row 64-group
    const int wng  = wave >> 1;     // col 64-group
    const int c    = lane & 15;
    const int q    = lane >> 4;

    const __bf16* pA = (const __bf16*)Xp + (size_t)(mt * 8) * STEP_ELEMS;
    const __bf16* pB = (const __bf16*)Bp + (size_t)kc * CLASS_ELEMS;

    // Tv preload: FOLD is pure VALU (no mid-loop vmcnt surprises)
    float tvr[4][4];
    #pragma unroll
    for (int ct4 = 0; ct4 < 4; ++ct4)
        #pragma unroll
        for (int ni = 0; ni < 4; ++ni)
            tvr[ct4][ni] = Tv[kc * 512 + ct4 * 128 + wng * 64 + ni * 16 + c];

    // LDS byte offsets of each fragment line (line*1024 + lane*16)
    int aoff[4][2], boff[4][2];
    #pragma unroll
    for (int mi = 0; mi < 4; ++mi)
        #pragma unroll
        for (int h = 0; h < 2; ++h)
            aoff[mi][h] = (((wmg * 4 + mi) * 2 + h) * 64 + lane) * 16;
    #pragma unroll
    for (int ni = 0; ni < 4; ++ni)
        #pragma unroll
        for (int h = 0; h < 2; ++h)
            boff[ni][h] = (((wng * 4 + ni) * 2 + h) * 64 + lane) * 16;

    f32x4 acc[4][4];
    #pragma unroll
    for (int mi = 0; mi < 4; ++mi)
        #pragma unroll
        for (int ni = 0; ni < 4; ++ni)
            acc[mi][ni] = (f32x4){0.f, 0.f, 0.f, 0.f};
    float rsum[16];
    #pragma unroll
    for (int i = 0; i < 16; ++i) rsum[i] = 0.f;

    bf16x8 fa[4][2], fb[4][2];

// stage step SIDX into buffer BUF: 8 global_load_lds_dwordx4 per wave
// (4 A-chunks + 4 B-chunks of 1 KB, wave-uniform LDS dest + lane*16 HW offset)
#define STAGE(BUF, SIDX) {                                                     \
    const int kch_ = kch_of(SIDX);                                             \
    const char* ga_ = (const char*)(pA + (size_t)kch_ * STEP_ELEMS);           \
    const char* gb_ = (const char*)(pB + (size_t)(SIDX) * STEP_ELEMS);         \
    char* la_ = &ldsbuf[BUF][0];                                               \
    char* lb_ = &ldsbuf[BUF][16384];                                           \
    _Pragma("unroll") for (int i_ = 0; i_ < 4; ++i_) {                         \
        const int ch_ = (wave * 4 + i_) * 1024;                                \
        __builtin_amdgcn_global_load_lds(                                      \
            (const __attribute__((address_space(1))) void*)(ga_ + ch_ + lane * 16), \
            (__attribute__((address_space(3))) void*)(la_ + ch_), 16, 0, 0);   \
        __builtin_amdgcn_global_load_lds(                                      \
            (const __attribute__((address_space(1))) void*)(gb_ + ch_ + lane * 16), \
            (__attribute__((address_space(3))) void*)(lb_ + ch_), 16, 0, 0);   \
    } }

#define LDS_FRAGS(BUF) {                                                       \
    const char* la_ = &ldsbuf[BUF][0];                                         \
    const char* lb_ = &ldsbuf[BUF][16384];                                     \
    _Pragma("unroll") for (int mi = 0; mi < 4; ++mi)                           \
    _Pragma("unroll") for (int h = 0; h < 2; ++h)                              \
        fa[mi][h] = *(const bf16x8*)(la_ + aoff[mi][h]);                       \
    _Pragma("unroll") for (int ni = 0; ni < 4; ++ni)                           \
    _Pragma("unroll") for (int h = 0; h < 2; ++h)                              \
        fb[ni][h] = *(const bf16x8*)(lb_ + boff[ni][h]); }

#define MFMA_ALL                                                               \
    _Pragma("unroll") for (int mi = 0; mi < 4; ++mi)                           \
    _Pragma("unroll") for (int ni = 0; ni < 4; ++ni)                           \
    _Pragma("unroll") for (int h = 0; h < 2; ++h)                              \
        acc[mi][ni] = __builtin_amdgcn_mfma_f32_16x16x32_bf16(                 \
            fa[mi][h], fb[ni][h], acc[mi][ni], 0, 0, 0);

    // fold: subtract t and square-accumulate; C/D layout col=c(e), row=q*4+r(b)
#define FOLD(CT) {                                                             \
    _Pragma("unroll") for (int mi = 0; mi < 4; ++mi)                           \
    _Pragma("unroll") for (int ni = 0; ni < 4; ++ni)                           \
    _Pragma("unroll") for (int r = 0; r < 4; ++r) {                            \
        float y_ = acc[mi][ni][r] - tvr[CT][ni];                               \
        rsum[mi * 4 + r] += y_ * y_;                                           \
        acc[mi][ni][r] = 0.f; } }

    STAGE(0, 0);

    #pragma unroll
    for (int s = 0; s < NSTEPS; ++s) {
        const int cur = s & 1;
        // fold boundaries (8, 14, 18): pure VALU, overlaps with staging latency
        if (s == 8)       { FOLD(0); }
        else if (s == 14) { FOLD(1); }
        else if (s == 18) { FOLD(2); }

        if (s + 1 < NSTEPS) {
            STAGE(cur ^ 1, s + 1);
            // drain everything except the 8 just-issued next-stage loads:
            // invariant -> buf[cur] fully staged, next stays in flight
            asm volatile("s_waitcnt vmcnt(8)" ::: "memory");
        } else {
            asm volatile("s_waitcnt vmcnt(0)" ::: "memory");
        }
        __builtin_amdgcn_s_barrier();      // all waves: buf[cur] ready

        LDS_FRAGS(cur);                    // 16x ds_read_b128, conflict-free
        MFMA_ALL;                          // compiler inserts lgkm waits

        __builtin_amdgcn_s_barrier();      // all waves done reading buf[cur]
    }
    FOLD(3);

    // reduce the 16 e-lanes of each quad
    #pragma unroll
    for (int i = 0; i < 16; ++i) {
        float v = rsum[i];
        v += __shfl_xor(v, 1, 64);
        v += __shfl_xor(v, 2, 64);
        v += __shfl_xor(v, 4, 64);
        v += __shfl_xor(v, 8, 64);
        rsum[i] = v;
    }
    // osum aliases the staging LDS (all fragment reads done: last barrier above)
    float (*osum)[128] = (float(*)[128])&ldsbuf[0][0];
    if (c == 0) {
        #pragma unroll
        for (int mi = 0; mi < 4; ++mi)
            #pragma unroll
            for (int r = 0; r < 4; ++r)
                osum[wng][wmg * 64 + mi * 16 + q * 4 + r] = rsum[mi * 4 + r];
    }
    __syncthreads();
    if (tid < 128) {
        float v = osum[0][tid] + osum[1][tid];
        Out[(size_t)(mt * 128 + tid) * KC_SZ + kc] = sqrtf(v);
    }
}

// ---------------------------------------------------------------------------
// Fallback (round-2 kernel, proven, ws-independent).
// ---------------------------------------------------------------------------
#define FLDA 40
#define BM 128
#define BN 128
__device__ __forceinline__ void fstep_map(int s, int& ct, int& k0) {
    if (s < 16)      { ct = 0; k0 = s * 32; }
    else if (s < 28) { ct = 1; k0 = 128 + (s - 16) * 32; }
    else if (s < 36) { ct = 2; k0 = 256 + (s - 28) * 32; }
    else             { ct = 3; k0 = 384 + (s - 36) * 32; }
}
__global__ __launch_bounds__(256, 2)
void gml2_fallback(const float* __restrict__ X, const float* __restrict__ W,
                   const float* __restrict__ Ldiag, const float* __restrict__ Llow,
                   float* __restrict__ Out) {
    __shared__ __bf16 As[BM * FLDA];
    __shared__ __bf16 Bs[BN * FLDA];
    __shared__ float  Ws[D_SZ];
    __shared__ float  osum[2][BM];
    const int tid = threadIdx.x;
    const int bx  = blockIdx.x;
    const int xcd = bx & 7;
    const int g   = bx >> 3;
    const int kc  = xcd * 32 + (g >> 3);
    const int mt  = g & 7;
    const int lane = tid & 63, wave = tid >> 6;
    const int wm = (wave & 1) * 64, wn = (wave >> 1) * 64;
    const int c = lane & 15, q = lane >> 4;
    const int am = tid >> 1, akh = (tid & 1) << 4;
    const float* xrow = X + (size_t)(mt * BM + am) * D_SZ;
    const float* wrow = W + (size_t)kc * D_SZ;
    const int be = tid & 127, bd = (tid >> 7) << 4;
    const float* lowbase  = Llow  + (size_t)kc * NLOW;
    const float* diagbase = Ldiag + (size_t)kc * D_SZ;
    if (tid < 128) ((f32x4*)Ws)[tid] = ((const f32x4*)wrow)[tid];
    float rsum[16];
    #pragma unroll
    for (int i = 0; i < 16; ++i) rsum[i] = 0.f;
    f32x4 acc[4][4];
    #pragma unroll
    for (int mi = 0; mi < 4; ++mi)
        #pragma unroll
        for (int ni = 0; ni < 4; ++ni) acc[mi][ni] = (f32x4){0.f, 0.f, 0.f, 0.f};
    f32x4 xr[4];
    float bb[16];
    auto prefetch = [&](int s) {
        int pct, pk0; fstep_map(s, pct, pk0);
        const int pe0 = pct * BN;
        const float* xp = xrow + pk0 + akh;
        #pragma unroll
        for (int i = 0; i < 4; ++i) xr[i] = ((const f32x4*)xp)[i];
        const int e = pe0 + be, d0 = pk0 + bd;
        int tri = (d0 * (d0 - 1)) >> 1;
        if (pk0 >= pe0 + BN) {
            #pragma unroll
            for (int j = 0; j < 16; ++j) { bb[j] = lowbase[tri + e]; tri += d0 + j; }
        } else {
            #pragma unroll
            for (int j = 0; j < 16; ++j) {
                const int d = d0 + j;
                float val = 0.f;
                if (d > e)       val = lowbase[tri + e];
                else if (d == e) { float dq = diagbase[d]; val = dq * dq; }
                bb[j] = val; tri += d;
            }
        }
    };
    prefetch(0);
    __syncthreads();
    int cur_ct = 0;
    for (int s = 0; s < 40; ++s) {
        int ct, k0; fstep_map(s, ct, k0);
        if (ct != cur_ct) {
            #pragma unroll
            for (int mi = 0; mi < 4; ++mi)
                #pragma unroll
                for (int ni = 0; ni < 4; ++ni)
                    #pragma unroll
                    for (int r = 0; r < 4; ++r) {
                        float y = acc[mi][ni][r];
                        rsum[mi * 4 + r] += y * y;
                        acc[mi][ni][r] = 0.f;
                    }
            cur_ct = ct;
        }
        bf16x8 ap0, ap1;
        {
            const f32x4* wsp = (const f32x4*)&Ws[k0 + akh];
            #pragma unroll
            for (int i = 0; i < 4; ++i) {
                f32x4 wv = wsp[i];
                #pragma unroll
                for (int l = 0; l < 4; ++l) {
                    float v = xr[i][l] - wv[l];
                    int idx = i * 4 + l;
                    if (idx < 8) ap0[idx] = (__bf16)v;
                    else         ap1[idx - 8] = (__bf16)v;
                }
            }
        }
        bf16x8 bp0, bp1;
        #pragma unroll
        for (int j = 0; j < 8; ++j) { bp0[j] = (__bf16)bb[j]; bp1[j] = (__bf16)bb[j + 8]; }
        __syncthreads();
        *(bf16x8*)&As[am * FLDA + akh]     = ap0;
        *(bf16x8*)&As[am * FLDA + akh + 8] = ap1;
        *(bf16x8*)&Bs[be * FLDA + bd]      = bp0;
        *(bf16x8*)&Bs[be * FLDA + bd + 8]  = bp1;
        if (s + 1 < 40) prefetch(s + 1);
        __syncthreads();
        bf16x8 af[4], bfr[4];
        #pragma unroll
        for (int mi = 0; mi < 4; ++mi)
            af[mi] = *(const bf16x8*)&As[(wm + mi * 16 + c) * FLDA + q * 8];
        #pragma unroll
        for (int ni = 0; ni < 4; ++ni)
            bfr[ni] = *(const bf16x8*)&Bs[(wn + ni * 16 + c) * FLDA + q * 8];
        #pragma unroll
        for (int mi = 0; mi < 4; ++mi)
            #pragma unroll
            for (int ni = 0; ni < 4; ++ni)
                acc[mi][ni] = __builtin_amdgcn_mfma_f32_16x16x32_bf16(
                    af[mi], bfr[ni], acc[mi][ni], 0, 0, 0);
    }
    #pragma unroll
    for (int mi = 0; mi < 4; ++mi)
        #pragma unroll
        for (int ni = 0; ni < 4; ++ni)
            #pragma unroll
            for (int r = 0; r < 4; ++r) {
                float y = acc[mi][ni][r];
                rsum[mi * 4 + r] += y * y;
            }
    #pragma unroll
    for (int i = 0; i < 16; ++i) {
        float s = rsum[i];
        s += __shfl_xor(s, 1, 64);
        s += __shfl_xor(s, 2, 64);
        s += __shfl_xor(s, 4, 64);
        s += __shfl_xor(s, 8, 64);
        rsum[i] = s;
    }
    const int wnIdx = wave >> 1;
    if (c == 0) {
        #pragma unroll
        for (int mi = 0; mi < 4; ++mi)
            #pragma unroll
            for (int r = 0; r < 4; ++r)
                osum[wnIdx][wm + mi * 16 + q * 4 + r] = rsum[mi * 4 + r];
    }
    __syncthreads();
    if (tid < BM) {
        float s = osum[0][tid] + osum[1][tid];
        Out[(size_t)(mt * BM + tid) * KC_SZ + kc] = sqrtf(s);
    }
}

extern "C" void kernel_launch(void* const* d_in, const int* in_sizes, int n_in,
                              void* d_out, int out_size, void* d_ws, size_t ws_size,
                              hipStream_t stream) {
    const float* X  = (const float*)d_in[0];   // [1024, 512]
    const float* W  = (const float*)d_in[1];   // [256, 1, 512]
    const float* Ld = (const float*)d_in[2];   // [256, 512]
    const float* Ll = (const float*)d_in[3];   // [256, 130816]
    float* Out = (float*)d_out;                // [1024, 256]

    if (ws_size >= WS_NEED) {
        __hip_bfloat16* Bp    = (__hip_bfloat16*)d_ws;
        __hip_bfloat16* Xp    = (__hip_bfloat16*)((char*)d_ws + OFF_XP);
        float*          tpart = (float*)((char*)d_ws + OFF_TPART);
        float*          Tvv   = (float*)((char*)d_ws + OFF_T);
        prep_all<<<dim3(64 + NSTEPS * KC_SZ), dim3(256), 0, stream>>>(
            X, Ld, Ll, W, Xp, Bp, tpart);
        t_reduce<<<dim3(512),        dim3(256), 0, stream>>>(tpart, Tvv);
        gml2_main<<<dim3(KC_SZ * 8), dim3(256), 0, stream>>>(Xp, Bp, Tvv, Out);
    } else {
        gml2_fallback<<<dim3(KC_SZ * 8), dim3(256), 0, stream>>>(X, W, Ld, Ll, Out);
    }
}

// Round 12
// 296.010 us; speedup vs baseline: 1.0459x; 1.0459x over previous
//
#include <hip/hip_runtime.h>
#include <hip/hip_bf16.h>
#include <math.h>

// Problem constants
#define B_SZ   1024
#define D_SZ   512
#define KC_SZ  256
#define NLOW   130816            // 512*511/2

// B pages: per class, 20 K-step pages of 16 KB, stored in per-wave MFMA
// fragment order: line = ((wng*4+ni)*2+h)*64 + lane, lane = q*16+c,
// value[j] = L[d][e], e = wng*64+ni*16+c, d_local = h*32+q*8+j.
#define STEP_ELEMS  8192
#define NSTEPS      20           // 8+6+4+2 triangular K-steps
#define CLASS_ELEMS (NSTEPS * STEP_ELEMS)   // 320 KB/class

// Workspace layout (bytes)
#define OFF_XP     (size_t)(KC_SZ * CLASS_ELEMS * 2)        // 83886080
#define OFF_TPART  (OFF_XP + 64 * STEP_ELEMS * 2)           // +1 MiB
#define OFF_T      (OFF_TPART + (size_t)KC_SZ * 8 * 512 * 4)// +4 MiB
#define WS_NEED    (OFF_T + (size_t)KC_SZ * 512 * 4)        // ~85.5 MiB

typedef __attribute__((ext_vector_type(4))) float  f32x4;
typedef __attribute__((ext_vector_type(4), aligned(4))) float f32x4u; // align-4 vector load
typedef __attribute__((ext_vector_type(8))) __bf16 bf16x8;

// steps before col-tile ct
__device__ __forceinline__ int sbase_of(int ct) { return ct * (9 - ct); }
// s -> dt (also the A-page k-chunk)
__device__ __forceinline__ int kch_of(int s) {
    return (s < 8) ? s : (s < 14) ? s - 6 : (s < 18) ? s - 10 : s - 12;
}

// ---------------------------------------------------------------------------
// K1: fused prep (round-7/9 exact, measured in the 300.4 us composition).
// Blocks [0,64): X pages. Blocks [64, 64+20*256): B pages + t-partials.
// ---------------------------------------------------------------------------
__global__ __launch_bounds__(256)
void prep_all(const float* __restrict__ X,
              const float* __restrict__ Ldiag,
              const float* __restrict__ Llow,
              const float* __restrict__ W,
              __hip_bfloat16* __restrict__ Xp,
              __hip_bfloat16* __restrict__ Bp,
              float* __restrict__ tpart) {
    __shared__ __bf16 Lt[128 * 64];      // [e_local][d_local], 16B-block XOR swizzle
    __shared__ float  ptl[32 * 129];     // [m][e_local], padded: bank=(m+e)%32

    const int bx  = blockIdx.x;
    const int tid = threadIdx.x;

    if (bx < 64) {
        // ---- prep_x: page pg = bx, 4 lines per thread ----
        const int pg  = bx;              // mt*8 + kch
        const int mt  = pg >> 3, kch = pg & 7;
        __bf16* out = (__bf16*)Xp + (size_t)pg * STEP_ELEMS;
        #pragma unroll
        for (int i = 0; i < 4; ++i) {
            const int line = tid + i * 256;          // 0..1023
            const int wmg = line >> 9, mi = (line >> 7) & 3, h = (line >> 6) & 1;
            const int lane = line & 63, q = lane >> 4, c = lane & 15;
            const int row = mt * 128 + wmg * 64 + mi * 16 + c;
            const float* src = X + (size_t)row * D_SZ + kch * 64 + h * 32 + q * 8;
            f32x4 v0 = ((const f32x4*)src)[0];
            f32x4 v1 = ((const f32x4*)src)[1];
            bf16x8 p;
            #pragma unroll
            for (int j = 0; j < 4; ++j) { p[j] = (__bf16)v0[j]; p[j + 4] = (__bf16)v1[j]; }
            *(bf16x8*)(out + line * 8) = p;
        }
        return;
    }

    // ---- prep_b: page s of class kc ----
    const int idx = bx - 64;
    const int s   = idx % 20;
    const int kc  = idx / 20;
    const int ct = (s < 8) ? 0 : (s < 14) ? 1 : (s < 18) ? 2 : 3;
    const int dt = kch_of(s);
    const int e0 = ct << 7, d0 = dt << 6;

    const int m   = tid & 31;            // d row-pair index
    const int seg = tid >> 5;            // e 16-chunk index
    const int es  = seg << 4;            // e_local chunk start
    const int dg0 = d0 + 2 * m;          // global d of row 0 (row 1 = dg0+1)

    // classify this thread's 16-e chunk:
    // 0 = pure strict-lower (vector loads), 1 = straddles diagonal, 2 = zero
    int cls;
    if (dt >= 2 * ct + 2)      cls = 0;
    else if (dt == 2 * ct + 1) cls = (seg < 4) ? 0 : 1;
    else                       cls = (seg < 4) ? 1 : 2;

    const float* lowb = Llow + (size_t)kc * NLOW;
    const float2 wv = *(const float2*)(W + (size_t)kc * D_SZ + dg0);

    float v0[16], v1[16];
    if (cls == 0) {
        const int t0 = (dg0 * (dg0 - 1)) >> 1;       // tri(dg0)
        const int t1 = t0 + dg0;                     // tri(dg0+1)
        const float* s0 = lowb + t0 + e0 + es;
        const float* s1 = lowb + t1 + e0 + es;
        #pragma unroll
        for (int i = 0; i < 4; ++i) {
            f32x4u a = ((const f32x4u*)s0)[i];
            f32x4u b = ((const f32x4u*)s1)[i];
            #pragma unroll
            for (int j = 0; j < 4; ++j) { v0[i * 4 + j] = a[j]; v1[i * 4 + j] = b[j]; }
        }
    } else if (cls == 1) {
        const int t0 = (dg0 * (dg0 - 1)) >> 1;
        const int t1 = t0 + dg0;
        const float* diagb = Ldiag + (size_t)kc * D_SZ;
        float q0 = diagb[dg0],     q1 = diagb[dg0 + 1];
        q0 *= q0; q1 *= q1;
        #pragma unroll
        for (int j = 0; j < 16; ++j) {
            const int eg = e0 + es + j;
            v0[j] = (eg < dg0)     ? lowb[t0 + eg] : ((eg == dg0)     ? q0 : 0.f);
            v1[j] = (eg < dg0 + 1) ? lowb[t1 + eg] : ((eg == dg0 + 1) ? q1 : 0.f);
        }
    } else {
        #pragma unroll
        for (int j = 0; j < 16; ++j) { v0[j] = 0.f; v1[j] = 0.f; }
    }

    // transposed bf16 pair writes (conflict-free) + fp32 t-partials
    char* ltb = (char*)Lt;
    #pragma unroll
    for (int j = 0; j < 16; ++j) {
        const int el = es + j;
        union { __bf16 h[2]; unsigned u; } pk;
        pk.h[0] = (__bf16)v0[j];
        pk.h[1] = (__bf16)v1[j];
        const int off = el * 128 + ((4 * m) ^ ((el & 7) << 4));
        *(unsigned*)(ltb + off) = pk.u;
        ptl[m * 129 + el] = wv.x * v0[j] + wv.y * v1[j];
    }
    __syncthreads();

    // fragment-order page out: 4 lines/thread, one ds_read_b128 + 16B store each
    __bf16* page = (__bf16*)Bp + (size_t)kc * CLASS_ELEMS + (size_t)s * STEP_ELEMS;
    const int lane = tid & 63, q = lane >> 4, c = lane & 15;
    #pragma unroll
    for (int k = 0; k < 4; ++k) {
        const int ln = k * 256 + tid;
        const int up = ln >> 6;
        const int h  = up & 1;
        const int el = ((up >> 3) << 6) + (((up >> 1) & 3) << 4) + c;
        const int off = el * 128 + (((h << 6) + (q << 4)) ^ ((el & 7) << 4));
        *(bf16x8*)(page + (size_t)ln * 8) = *(const bf16x8*)(ltb + off);
    }

    // t-partial reduce over the 32 row-pairs (tpart layout unchanged)
    if (tid < 128) {
        float sum = 0.f;
        #pragma unroll
        for (int mm = 0; mm < 32; ++mm) sum += ptl[mm * 129 + tid];
        tpart[((size_t)(kc * 8 + dt)) * 512 + e0 + tid] = sum;
    }
}

// ---------------------------------------------------------------------------
// K1c: t[kc][e] = sum over valid dt of tpart[kc][dt][e]  (separate tiny
// launch -- round-7 showed folding this into main's prologue perturbs the
// main loop's schedule: MfmaUtil 43->36, +15 us)
// ---------------------------------------------------------------------------
__global__ __launch_bounds__(256)
void t_reduce(const float* __restrict__ tpart, float* __restrict__ Tv) {
    const int idx = blockIdx.x * 256 + threadIdx.x;   // 131072 total
    const int kc = idx >> 9, e = idx & 511;
    const int ct = e >> 7;
    float s = 0.f;
    for (int dt = ct << 1; dt < 8; ++dt)
        s += tpart[((size_t)(kc * 8 + dt)) * 512 + e];
    Tv[idx] = s;
}

// ---------------------------------------------------------------------------
// K2: main GEMM -- ROUND-3 VERBATIM (measured 85.7 us, VGPR 116, WRITE 3.3 MB,
// MfmaUtil 44%). FROZEN: rounds 4/5/8 prove >128 arch VGPRs spills; rounds
// 7/11 prove the loop schedule is perturbation-fragile (even sibling-kernel
// edits in the same module shifted main 86 -> 105).
// ---------------------------------------------------------------------------
__global__ __launch_bounds__(256, 2)
void gml2_main(const __hip_bfloat16* __restrict__ Xp,
               const __hip_bfloat16* __restrict__ Bp,
               const float* __restrict__ Tv,
               float* __restrict__ Out) {
    // [buf][ A 16KB | B 16KB ] = 64 KB total; osum aliased after last barrier
    __shared__ __align__(16) char ldsbuf[2][32768];

    const int tid = threadIdx.x;
    const int bx  = blockIdx.x;
    // XCD swizzle: all 8 row-tiles of a class on one XCD -> pages L2-resident
    const int xcd = bx & 7;
    const int g   = bx >> 3;
    const int kc  = xcd * 32 + (g >> 3);
    const int mt  = g & 7;

    const int lane = tid & 63;
    const int wave = tid >> 6;
    const int wmg  = wave & 1;      // row 64-group
    const int wng  = wave >> 1;     // col 64-group
    const int c    = lane & 15;
    const int q    = lane >> 4;

    const __bf16* pA = (const __bf16*)Xp + (size_t)(mt * 8) * STEP_ELEMS;
    const __bf16* pB = (const __bf16*)Bp + (size_t)kc * CLASS_ELEMS;

    // Tv preload: FOLD is pure VALU (no mid-loop vmcnt surprises)
    float tvr[4][4];
    #pragma unroll
    for (int ct4 = 0; ct4 < 4; ++ct4)
        #pragma unroll
        for (int ni = 0; ni < 4; ++ni)
            tvr[ct4][ni] = Tv[kc * 512 + ct4 * 128 + wng * 64 + ni * 16 + c];

    // LDS byte offsets of each fragment line (line*1024 + lane*16)
    int aoff[4][2], boff[4][2];
    #pragma unroll
    for (int mi = 0; mi < 4; ++mi)
        #pragma unroll
        for (int h = 0; h < 2; ++h)
            aoff[mi][h] = (((wmg * 4 + mi) * 2 + h) * 64 + lane) * 16;
    #pragma unroll
    for (int ni = 0; ni < 4; ++ni)
        #pragma unroll
        for (int h = 0; h < 2; ++h)
            boff[ni][h] = (((wng * 4 + ni) * 2 + h) * 64 + lane) * 16;

    f32x4 acc[4][4];
    #pragma unroll
    for (int mi = 0; mi < 4; ++mi)
        #pragma unroll
        for (int ni = 0; ni < 4; ++ni)
            acc[mi][ni] = (f32x4){0.f, 0.f, 0.f, 0.f};
    float rsum[16];
    #pragma unroll
    for (int i = 0; i < 16; ++i) rsum[i] = 0.f;

    bf16x8 fa[4][2], fb[4][2];

// stage step SIDX into buffer BUF: 8 global_load_lds_dwordx4 per wave
// (4 A-chunks + 4 B-chunks of 1 KB, wave-uniform LDS dest + lane*16 HW offset)
#define STAGE(BUF, SIDX) {                                                     \
    const int kch_ = kch_of(SIDX);                                             \
    const char* ga_ = (const char*)(pA + (size_t)kch_ * STEP_ELEMS);           \
    const char* gb_ = (const char*)(pB + (size_t)(SIDX) * STEP_ELEMS);         \
    char* la_ = &ldsbuf[BUF][0];                                               \
    char* lb_ = &ldsbuf[BUF][16384];                                           \
    _Pragma("unroll") for (int i_ = 0; i_ < 4; ++i_) {                         \
        const int ch_ = (wave * 4 + i_) * 1024;                                \
        __builtin_amdgcn_global_load_lds(                                      \
            (const __attribute__((address_space(1))) void*)(ga_ + ch_ + lane * 16), \
            (__attribute__((address_space(3))) void*)(la_ + ch_), 16, 0, 0);   \
        __builtin_amdgcn_global_load_lds(                                      \
            (const __attribute__((address_space(1))) void*)(gb_ + ch_ + lane * 16), \
            (__attribute__((address_space(3))) void*)(lb_ + ch_), 16, 0, 0);   \
    } }

#define LDS_FRAGS(BUF) {                                                       \
    const char* la_ = &ldsbuf[BUF][0];                                         \
    const char* lb_ = &ldsbuf[BUF][16384];                                     \
    _Pragma("unroll") for (int mi = 0; mi < 4; ++mi)                           \
    _Pragma("unroll") for (int h = 0; h < 2; ++h)                              \
        fa[mi][h] = *(const bf16x8*)(la_ + aoff[mi][h]);                       \
    _Pragma("unroll") for (int ni = 0; ni < 4; ++ni)                           \
    _Pragma("unroll") for (int h = 0; h < 2; ++h)                              \
        fb[ni][h] = *(const bf16x8*)(lb_ + boff[ni][h]); }

#define MFMA_ALL                                                               \
    _Pragma("unroll") for (int mi = 0; mi < 4; ++mi)                           \
    _Pragma("unroll") for (int ni = 0; ni < 4; ++ni)                           \
    _Pragma("unroll") for (int h = 0; h < 2; ++h)                              \
        acc[mi][ni] = __builtin_amdgcn_mfma_f32_16x16x32_bf16(                 \
            fa[mi][h], fb[ni][h], acc[mi][ni], 0, 0, 0);

    // fold: subtract t and square-accumulate; C/D layout col=c(e), row=q*4+r(b)
#define FOLD(CT) {                                                             \
    _Pragma("unroll") for (int mi = 0; mi < 4; ++mi)                           \
    _Pragma("unroll") for (int ni = 0; ni < 4; ++ni)                           \
    _Pragma("unroll") for (int r = 0; r < 4; ++r) {                            \
        float y_ = acc[mi][ni][r] - tvr[CT][ni];                               \
        rsum[mi * 4 + r] += y_ * y_;                                           \
        acc[mi][ni][r] = 0.f; } }

    STAGE(0, 0);

    #pragma unroll
    for (int s = 0; s < NSTEPS; ++s) {
        const int cur = s & 1;
        // fold boundaries (8, 14, 18): pure VALU, overlaps with staging latency
        if (s == 8)       { FOLD(0); }
        else if (s == 14) { FOLD(1); }
        else if (s == 18) { FOLD(2); }

        if (s + 1 < NSTEPS) {
            STAGE(cur ^ 1, s + 1);
            // drain everything except the 8 just-issued next-stage loads:
            // invariant -> buf[cur] fully staged, next stays in flight
            asm volatile("s_waitcnt vmcnt(8)" ::: "memory");
        } else {
            asm volatile("s_waitcnt vmcnt(0)" ::: "memory");
        }
        __builtin_amdgcn_s_barrier();      // all waves: buf[cur] ready

        LDS_FRAGS(cur);                    // 16x ds_read_b128, conflict-free
        MFMA_ALL;                          // compiler inserts lgkm waits

        __builtin_amdgcn_s_barrier();      // all waves done reading buf[cur]
    }
    FOLD(3);

    // reduce the 16 e-lanes of each quad
    #pragma unroll
    for (int i = 0; i < 16; ++i) {
        float v = rsum[i];
        v += __shfl_xor(v, 1, 64);
        v += __shfl_xor(v, 2, 64);
        v += __shfl_xor(v, 4, 64);
        v += __shfl_xor(v, 8, 64);
        rsum[i] = v;
    }
    // osum aliases the staging LDS (all fragment reads done: last barrier above)
    float (*osum)[128] = (float(*)[128])&ldsbuf[0][0];
    if (c == 0) {
        #pragma unroll
        for (int mi = 0; mi < 4; ++mi)
            #pragma unroll
            for (int r = 0; r < 4; ++r)
                osum[wng][wmg * 64 + mi * 16 + q * 4 + r] = rsum[mi * 4 + r];
    }
    __syncthreads();
    if (tid < 128) {
        float v = osum[0][tid] + osum[1][tid];
        Out[(size_t)(mt * 128 + tid) * KC_SZ + kc] = sqrtf(v);
    }
}

// ---------------------------------------------------------------------------
// Fallback (round-2 kernel, proven, ws-independent).
// ---------------------------------------------------------------------------
#define FLDA 40
#define BM 128
#define BN 128
__device__ __forceinline__ void fstep_map(int s, int& ct, int& k0) {
    if (s < 16)      { ct = 0; k0 = s * 32; }
    else if (s < 28) { ct = 1; k0 = 128 + (s - 16) * 32; }
    else if (s < 36) { ct = 2; k0 = 256 + (s - 28) * 32; }
    else             { ct = 3; k0 = 384 + (s - 36) * 32; }
}
__global__ __launch_bounds__(256, 2)
void gml2_fallback(const float* __restrict__ X, const float* __restrict__ W,
                   const float* __restrict__ Ldiag, const float* __restrict__ Llow,
                   float* __restrict__ Out) {
    __shared__ __bf16 As[BM * FLDA];
    __shared__ __bf16 Bs[BN * FLDA];
    __shared__ float  Ws[D_SZ];
    __shared__ float  osum[2][BM];
    const int tid = threadIdx.x;
    const int bx  = blockIdx.x;
    const int xcd = bx & 7;
    const int g   = bx >> 3;
    const int kc  = xcd * 32 + (g >> 3);
    const int mt  = g & 7;
    const int lane = tid & 63, wave = tid >> 6;
    const int wm = (wave & 1) * 64, wn = (wave >> 1) * 64;
    const int c = lane & 15, q = lane >> 4;
    const int am = tid >> 1, akh = (tid & 1) << 4;
    const float* xrow = X + (size_t)(mt * BM + am) * D_SZ;
    const float* wrow = W + (size_t)kc * D_SZ;
    const int be = tid & 127, bd = (tid >> 7) << 4;
    const float* lowbase  = Llow  + (size_t)kc * NLOW;
    const float* diagbase = Ldiag + (size_t)kc * D_SZ;
    if (tid < 128) ((f32x4*)Ws)[tid] = ((const f32x4*)wrow)[tid];
    float rsum[16];
    #pragma unroll
    for (int i = 0; i < 16; ++i) rsum[i] = 0.f;
    f32x4 acc[4][4];
    #pragma unroll
    for (int mi = 0; mi < 4; ++mi)
        #pragma unroll
        for (int ni = 0; ni < 4; ++ni) acc[mi][ni] = (f32x4){0.f, 0.f, 0.f, 0.f};
    f32x4 xr[4];
    float bb[16];
    auto prefetch = [&](int s) {
        int pct, pk0; fstep_map(s, pct, pk0);
        const int pe0 = pct * BN;
        const float* xp = xrow + pk0 + akh;
        #pragma unroll
        for (int i = 0; i < 4; ++i) xr[i] = ((const f32x4*)xp)[i];
        const int e = pe0 + be, d0 = pk0 + bd;
        int tri = (d0 * (d0 - 1)) >> 1;
        if (pk0 >= pe0 + BN) {
            #pragma unroll
            for (int j = 0; j < 16; ++j) { bb[j] = lowbase[tri + e]; tri += d0 + j; }
        } else {
            #pragma unroll
            for (int j = 0; j < 16; ++j) {
                const int d = d0 + j;
                float val = 0.f;
                if (d > e)       val = lowbase[tri + e];
                else if (d == e) { float dq = diagbase[d]; val = dq * dq; }
                bb[j] = val; tri += d;
            }
        }
    };
    prefetch(0);
    __syncthreads();
    int cur_ct = 0;
    for (int s = 0; s < 40; ++s) {
        int ct, k0; fstep_map(s, ct, k0);
        if (ct != cur_ct) {
            #pragma unroll
            for (int mi = 0; mi < 4; ++mi)
                #pragma unroll
                for (int ni = 0; ni < 4; ++ni)
                    #pragma unroll
                    for (int r = 0; r < 4; ++r) {
                        float y = acc[mi][ni][r];
                        rsum[mi * 4 + r] += y * y;
                        acc[mi][ni][r] = 0.f;
                    }
            cur_ct = ct;
        }
        bf16x8 ap0, ap1;
        {
            const f32x4* wsp = (const f32x4*)&Ws[k0 + akh];
            #pragma unroll
            for (int i = 0; i < 4; ++i) {
                f32x4 wv = wsp[i];
                #pragma unroll
                for (int l = 0; l < 4; ++l) {
                    float v = xr[i][l] - wv[l];
                    int idx = i * 4 + l;
                    if (idx < 8) ap0[idx] = (__bf16)v;
                    else         ap1[idx - 8] = (__bf16)v;
                }
            }
        }
        bf16x8 bp0, bp1;
        #pragma unroll
        for (int j = 0; j < 8; ++j) { bp0[j] = (__bf16)bb[j]; bp1[j] = (__bf16)bb[j + 8]; }
        __syncthreads();
        *(bf16x8*)&As[am * FLDA + akh]     = ap0;
        *(bf16x8*)&As[am * FLDA + akh + 8] = ap1;
        *(bf16x8*)&Bs[be * FLDA + bd]      = bp0;
        *(bf16x8*)&Bs[be * FLDA + bd + 8]  = bp1;
        if (s + 1 < 40) prefetch(s + 1);
        __syncthreads();
        bf16x8 af[4], bfr[4];
        #pragma unroll
        for (int mi = 0; mi < 4; ++mi)
            af[mi] = *(const bf16x8*)&As[(wm + mi * 16 + c) * FLDA + q * 8];
        #pragma unroll
        for (int ni = 0; ni < 4; ++ni)
            bfr[ni] = *(const bf16x8*)&Bs[(wn + ni * 16 + c) * FLDA + q * 8];
        #pragma unroll
        for (int mi = 0; mi < 4; ++mi)
            #pragma unroll
            for (int ni = 0; ni < 4; ++ni)
                acc[mi][ni] = __builtin_amdgcn_mfma_f32_16x16x32_bf16(
                    af[mi], bfr[ni], acc[mi][ni], 0, 0, 0);
    }
    #pragma unroll
    for (int mi = 0; mi < 4; ++mi)
        #pragma unroll
        for (int ni = 0; ni < 4; ++ni)
            #pragma unroll
            for (int r = 0; r < 4; ++r) {
                float y = acc[mi][ni][r];
                rsum[mi * 4 + r] += y * y;
            }
    #pragma unroll
    for (int i = 0; i < 16; ++i) {
        float s = rsum[i];
        s += __shfl_xor(s, 1, 64);
        s += __shfl_xor(s, 2, 64);
        s += __shfl_xor(s, 4, 64);
        s += __shfl_xor(s, 8, 64);
        rsum[i] = s;
    }
    const int wnIdx = wave >> 1;
    if (c == 0) {
        #pragma unroll
        for (int mi = 0; mi < 4; ++mi)
            #pragma unroll
            for (int r = 0; r < 4; ++r)
                osum[wnIdx][wm + mi * 16 + q * 4 + r] = rsum[mi * 4 + r];
    }
    __syncthreads();
    if (tid < BM) {
        float s = osum[0][tid] + osum[1][tid];
        Out[(size_t)(mt * BM + tid) * KC_SZ + kc] = sqrtf(s);
    }
}

extern "C" void kernel_launch(void* const* d_in, const int* in_sizes, int n_in,
                              void* d_out, int out_size, void* d_ws, size_t ws_size,
                              hipStream_t stream) {
    const float* X  = (const float*)d_in[0];   // [1024, 512]
    const float* W  = (const float*)d_in[1];   // [256, 1, 512]
    const float* Ld = (const float*)d_in[2];   // [256, 512]
    const float* Ll = (const float*)d_in[3];   // [256, 130816]
    float* Out = (float*)d_out;                // [1024, 256]

    if (ws_size >= WS_NEED) {
        __hip_bfloat16* Bp    = (__hip_bfloat16*)d_ws;
        __hip_bfloat16* Xp    = (__hip_bfloat16*)((char*)d_ws + OFF_XP);
        float*          tpart = (float*)((char*)d_ws + OFF_TPART);
        float*          Tvv   = (float*)((char*)d_ws + OFF_T);
        prep_all<<<dim3(64 + NSTEPS * KC_SZ), dim3(256), 0, stream>>>(
            X, Ld, Ll, W, Xp, Bp, tpart);
        t_reduce<<<dim3(512),        dim3(256), 0, stream>>>(tpart, Tvv);
        gml2_main<<<dim3(KC_SZ * 8), dim3(256), 0, stream>>>(Xp, Bp, Tvv, Out);
    } else {
        gml2_fallback<<<dim3(KC_SZ * 8), dim3(256), 0, stream>>>(X, W, Ld, Ll, Out);
    }
}